// Round 8
// baseline (123.281 us; speedup 1.0000x reference)
//
#include <hip/hip_runtime.h>

#define B_  16
#define C_  256
#define O_  256

typedef short    bf16x8 __attribute__((ext_vector_type(8)));
typedef float    f32x16 __attribute__((ext_vector_type(16)));
typedef unsigned u32x4  __attribute__((ext_vector_type(4)));

// xT layout: [b][cc][yphys 0..65][lh 0..1][col 0..65][8c] bf16
#define XROW_SH  1056
#define XBC_SH   (66 * XROW_SH)
#define XT_BYTES ((size_t)B_ * 16 * XBC_SH * 2)

#define WTILE_SH 9216
#define WORP_BYTES ((size_t)B_ * 16 * 4 * WTILE_SH * 2)

#define XBUF_SH  10752

__device__ __forceinline__ unsigned cvtpk(float lo, float hi) {
    unsigned r;
    asm("v_cvt_pk_bf16_f32 %0, %1, %2" : "=v"(r) : "v"(lo), "v"(hi));
    return r;
}

__device__ __forceinline__ void gload16(const void* g, void* l) {
    __builtin_amdgcn_global_load_lds(
        (const __attribute__((address_space(1))) unsigned int*)g,
        (__attribute__((address_space(3))) unsigned int*)l, 16, 0, 0);
}

// ---------------------------------------------------------------- xprep -----
// Thread = 1 pixel x 8 channels: coalesced row loads -> cvt_pk -> one 16B
// store in conv layout. Pool partials fused.
__global__ __launch_bounds__(256) void xprep_kernel(const float* __restrict__ x,
                                                    short* __restrict__ xT,
                                                    float* __restrict__ pooled4) {
    const int cg = blockIdx.x;
    const int b  = blockIdx.y;
    const int z  = blockIdx.z;
    const int t  = threadIdx.x;
    const int lane = t & 63, wv = t >> 6;
    const int cc = cg >> 1, lh = cg & 1;

    short* xTb = xT + (size_t)(b * 16 + cc) * XBC_SH;
    const float* xb = x + ((size_t)(b * C_ + cg * 8) << 12);

    {   // halo zeros for this (cc,lh) slice
        u32x4 zv = {0, 0, 0, 0};
        if (t < 32) {
            int r   = z * 16 + 1 + (t >> 1);
            int col = (t & 1) ? 65 : 0;
            *(u32x4*)&xTb[r * XROW_SH + lh * 528 + col * 8] = zv;
        }
        if (z == 0 || z == 3) {
            int row = (z == 0) ? 0 : 65;
            if (t < 66) *(u32x4*)&xTb[row * XROW_SH + lh * 528 + t * 8] = zv;
        }
    }

    float s[8] = {0.f, 0.f, 0.f, 0.f, 0.f, 0.f, 0.f, 0.f};
    const int px = lane;
#pragma unroll
    for (int r = 0; r < 4; ++r) {
        const int row = z * 16 + wv * 4 + r;
        const float* src = xb + row * 64 + px;
        float v[8];
#pragma unroll
        for (int i = 0; i < 8; ++i) { v[i] = src[(size_t)i << 12]; s[i] += v[i]; }
        u32x4 d = { cvtpk(v[0], v[1]), cvtpk(v[2], v[3]),
                    cvtpk(v[4], v[5]), cvtpk(v[6], v[7]) };
        *(u32x4*)&xTb[(row + 1) * XROW_SH + lh * 528 + (px + 1) * 8] = d;
    }

#pragma unroll
    for (int i = 0; i < 8; ++i)
#pragma unroll
        for (int off = 32; off; off >>= 1) s[i] += __shfl_xor(s[i], off, 64);

    __shared__ float pr[4][8];
    if (lane == 0) {
#pragma unroll
        for (int i = 0; i < 8; ++i) pr[wv][i] = s[i];
    }
    __syncthreads();
    if (t < 8) {
        float v = pr[0][t] + pr[1][t] + pr[2][t] + pr[3][t];
        pooled4[(z * B_ + b) * C_ + cg * 8 + t] = v * (1.0f / 4096.0f);
    }
}

// ---------------------------------------------------------------- mix -------
// Dedup'd: grid (cc=16, og=4) = 64 blocks. Each block stages its bank slice
// ONCE (4k x 16oc x 16c x 9tap), mixes per (oc,c) once per b, and scatters to
// all 16 b x 4 rotations (mixed value is rotation-invariant; only the dest
// tap index permutes). Bank L2 reads: 37.6 MB -> 9.4 MB.
__global__ __launch_bounds__(256) void mix_kernel(const float* __restrict__ bank,
                                                  const float* __restrict__ pooled4,
                                                  const float* __restrict__ W_fc,
                                                  const float* __restrict__ b_fc,
                                                  short* __restrict__ worp) {
    const int cc = blockIdx.x;   // channel-16 group
    const int og = blockIdx.y;   // oc-16 group
    const int t  = threadIdx.x;

    __shared__ float bankL[4 * 16 * 16 * 10];   // [k][oc_l][c16][tap pad10] 40960 B
    __shared__ float cfs[16][4];

    // ---- stage bank slice (9216 elements, coalesced-ish runs of 144)
    for (int i = t; i < 4 * 16 * 16 * 9; i += 256) {
        int k  = i / 2304, r = i % 2304;
        int oc = r / 144,  r2 = r % 144;
        int c  = r2 / 9,   tap = r2 % 9;
        bankL[((k * 16 + oc) * 16 + c) * 10 + tap] =
            bank[(((size_t)k * 64 + og * 16 + oc) * C_ + cc * 16 + c) * 9 + tap];
    }
    // ---- logits for all 16 b
    if (t < 64) {
        int b = t >> 2, k = t & 3;
        float s = b_fc[k];
        for (int c = 0; c < C_; ++c) {
            float pv = pooled4[b * C_ + c] + pooled4[(B_ + b) * C_ + c]
                     + pooled4[(2 * B_ + b) * C_ + c] + pooled4[(3 * B_ + b) * C_ + c];
            s += pv * W_fc[k * C_ + c];
        }
        cfs[b][k] = s;
    }
    __syncthreads();
    if (t < 16) {
        float l0 = cfs[t][0], l1 = cfs[t][1], l2 = cfs[t][2], l3 = cfs[t][3];
        float mx = fmaxf(fmaxf(l0, l1), fmaxf(l2, l3));
        float e0 = expf(l0 - mx), e1 = expf(l1 - mx);
        float e2 = expf(l2 - mx), e3 = expf(l3 - mx);
        float inv = 1.f / (e0 + e1 + e2 + e3);
        cfs[t][0] = e0 * inv; cfs[t][1] = e1 * inv;
        cfs[t][2] = e2 * inv; cfs[t][3] = e3 * inv;
    }
    __syncthreads();

    const int oc_l = t & 15;
    const int lhs  = (t >> 4) & 1;
    const int bg   = t >> 5;                 // 0..7, two b's each
    const int o64  = og * 16 + oc_l;

#pragma unroll
    for (int bb = 0; bb < 2; ++bb) {
        const int b = bg * 2 + bb;
        const float c0 = cfs[b][0], c1 = cfs[b][1], c2 = cfs[b][2], c3 = cfs[b][3];
        float mixed[8][9];
#pragma unroll
        for (int ci = 0; ci < 8; ++ci) {
            const float* p0 = &bankL[((0 * 16 + oc_l) * 16 + lhs * 8 + ci) * 10];
            const float* p1 = p0 + 16 * 16 * 10;
            const float* p2 = p0 + 2 * 16 * 16 * 10;
            const float* p3 = p0 + 3 * 16 * 16 * 10;
#pragma unroll
            for (int tp = 0; tp < 9; ++tp)
                mixed[ci][tp] = c0 * p0[tp] + c1 * p1[tp] + c2 * p2[tp] + c3 * p3[tp];
        }
#pragma unroll
        for (int oq = 0; oq < 4; ++oq) {
#pragma unroll
            for (int td = 0; td < 9; ++td) {
                const int ti = td / 3, tj = td % 3;
                int si, sj;                 // (si,sj) = rot^-1(ti,tj)
                if      (oq == 0) { si = ti;     sj = tj;     }
                else if (oq == 1) { si = tj;     sj = 2 - ti; }
                else if (oq == 2) { si = 2 - ti; sj = 2 - tj; }
                else              { si = 2 - tj; sj = ti;     }
                const int ts = si * 3 + sj;
                u32x4 d = { cvtpk(mixed[0][ts], mixed[1][ts]),
                            cvtpk(mixed[2][ts], mixed[3][ts]),
                            cvtpk(mixed[4][ts], mixed[5][ts]),
                            cvtpk(mixed[6][ts], mixed[7][ts]) };
                size_t base = ((((((size_t)b * 16 + cc) * 4 + oq) * 9 + td) * 2
                                + lhs) * 64 + o64) * 8;
                *(u32x4*)&worp[base] = d;
            }
        }
    }
}

// ---------------------------------------------------------------- conv ------
// 64 o x 512 px per block, 4 waves; gload_lds double-buffer, 1 barrier/chunk.
// B-rows held in a 3-buffer register ring: all rows for TAP1/TAP2 are issued
// >= 1 MFMA-cluster before use, so only TAP0 pays a post-barrier lgkm wait.
__global__ __launch_bounds__(256, 2)
void conv_mfma(const short* __restrict__ xT, const short* __restrict__ worp,
               float* __restrict__ out) {
    __shared__ short lds[2 * XBUF_SH + 2 * WTILE_SH];   // 79,872 B

    const int g    = blockIdx.x;
    const int w    = (g & 7) * 64 + (g >> 3);   // XCD swizzle (bijective)
    const int oq   = w & 3;
    const int m    = w >> 2;
    const int rowt = m & 7;
    const int b    = m >> 3;
    const int y0   = rowt * 8;

    const int t    = threadIdx.x;
    const int lane = t & 63;
    const int wid  = t >> 6;
    const int l31  = lane & 31;
    const int lh   = lane >> 5;

    const char* xsrcB = (const char*)xT
        + ((size_t)(b * 16) * XBC_SH + (size_t)y0 * XROW_SH) * 2 + lane * 16;
    const char* wsrcB = (const char*)worp
        + (((size_t)(b * 16) * 4) + oq) * (WTILE_SH * 2) + lane * 16;

#define STAGE(ccc, p)                                                           \
    { const char* xs = xsrcB + (size_t)(ccc) * (XBC_SH * 2);                    \
      const char* ws = wsrcB + (size_t)(ccc) * (4 * WTILE_SH * 2);              \
      char* xd = (char*)lds + (p) * (XBUF_SH * 2);                              \
      char* wd = (char*)lds + 2 * (XBUF_SH * 2) + (p) * (WTILE_SH * 2);         \
      for (int u = wid; u < 21; u += 4) gload16(xs + u * 1024, xd + u * 1024);  \
      for (int u = wid; u < 18; u += 4) gload16(ws + u * 1024, wd + u * 1024); }

#define BRD(r, s) (*(const bf16x8*)&xcur[(((r) * 2 + lh) * 66 + (s) + l31) * 8])
#define LOADROW(R, r)                                                           \
    { R[0] = BRD(r, 0);  R[1] = BRD(r, 1);  R[2] = BRD(r, 2);                   \
      R[3] = BRD(r, 32); R[4] = BRD(r, 33); R[5] = BRD(r, 34); }

#define TAPROW(i, RA, RB)                                                       \
    _Pragma("unroll")                                                           \
    for (int j = 0; j < 3; ++j) {                                               \
        const int tap = (i) * 3 + j;                                            \
        const short* wp = wcur + ((tap * 2 + lh) * 64 + l31) * 8;               \
        bf16x8 A0 = *(const bf16x8*)wp;                                         \
        bf16x8 A1 = *(const bf16x8*)(wp + 256);                                 \
        acc0[0] = __builtin_amdgcn_mfma_f32_32x32x16_bf16(A0, RA[j],     acc0[0], 0, 0, 0); \
        acc1[0] = __builtin_amdgcn_mfma_f32_32x32x16_bf16(A1, RA[j],     acc1[0], 0, 0, 0); \
        acc0[1] = __builtin_amdgcn_mfma_f32_32x32x16_bf16(A0, RA[3 + j], acc0[1], 0, 0, 0); \
        acc1[1] = __builtin_amdgcn_mfma_f32_32x32x16_bf16(A1, RA[3 + j], acc1[1], 0, 0, 0); \
        acc0[2] = __builtin_amdgcn_mfma_f32_32x32x16_bf16(A0, RB[j],     acc0[2], 0, 0, 0); \
        acc1[2] = __builtin_amdgcn_mfma_f32_32x32x16_bf16(A1, RB[j],     acc1[2], 0, 0, 0); \
        acc0[3] = __builtin_amdgcn_mfma_f32_32x32x16_bf16(A0, RB[3 + j], acc0[3], 0, 0, 0); \
        acc1[3] = __builtin_amdgcn_mfma_f32_32x32x16_bf16(A1, RB[3 + j], acc1[3], 0, 0, 0); \
    }

    f32x16 acc0[4] = {}, acc1[4] = {};

    STAGE(0, 0);
    __syncthreads();

    for (int cc = 0; cc < 16; ++cc) {
        const int p = cc & 1;
        const short* xcur = lds + p * XBUF_SH;
        const short* wcur = lds + 2 * XBUF_SH + p * WTILE_SH;

        bf16x8 Ra[6], Rb[6], Rc[6];
        LOADROW(Ra, 2 * wid);               // all TAP0/TAP1 rows issued up front
        LOADROW(Rb, 2 * wid + 1);
        LOADROW(Rc, 2 * wid + 2);
        if (cc < 15) STAGE(cc + 1, p ^ 1);
        __builtin_amdgcn_s_setprio(1);
        TAPROW(0, Ra, Rb)
        __builtin_amdgcn_s_setprio(0);
        LOADROW(Ra, 2 * wid + 3);           // row 3: issued 1 cluster before use
        __builtin_amdgcn_s_setprio(1);
        TAPROW(1, Rb, Rc)
        TAPROW(2, Rc, Ra)
        __builtin_amdgcn_s_setprio(0);
        __syncthreads();
    }
#undef STAGE
#undef BRD
#undef LOADROW
#undef TAPROW

#pragma unroll
    for (int pf = 0; pf < 4; ++pf) {
        const int yb  = y0 + 2 * wid + (pf >> 1);
        const int xcb = 32 * (pf & 1) + l31;
#pragma unroll
        for (int r = 0; r < 16; ++r) {
            const int orow = (r & 3) + 8 * (r >> 2) + 4 * lh;
            const int o0   = oq * 64 + orow;
            __builtin_nontemporal_store(acc0[pf][r],
                &out[((size_t)(b * O_ + o0)      << 12) + yb * 64 + xcb]);
            __builtin_nontemporal_store(acc1[pf][r],
                &out[((size_t)(b * O_ + o0 + 32) << 12) + yb * 64 + xcb]);
        }
    }
}

// ---------------------------------------------------------------- launch ----
extern "C" void kernel_launch(void* const* d_in, const int* in_sizes, int n_in,
                              void* d_out, int out_size, void* d_ws, size_t ws_size,
                              hipStream_t stream) {
    const float* x    = (const float*)d_in[0];
    const float* W_fc = (const float*)d_in[1];
    const float* b_fc = (const float*)d_in[2];
    const float* bank = (const float*)d_in[3];
    float* out = (float*)d_out;

    short* xTb     = (short*)d_ws;
    short* worp    = (short*)((char*)d_ws + XT_BYTES);
    float* pooled4 = (float*)((char*)d_ws + XT_BYTES + WORP_BYTES);

    xprep_kernel<<<dim3(32, 16, 4), 256, 0, stream>>>(x, xTb, pooled4);
    mix_kernel<<<dim3(16, 4), 256, 0, stream>>>(bank, pooled4, W_fc, b_fc, worp);
    conv_mfma<<<512, 256, 0, stream>>>(xTb, worp, out);
}

// Round 9
// 105.926 us; speedup vs baseline: 1.1638x; 1.1638x over previous
//
#include <hip/hip_runtime.h>

#define B_  16
#define C_  256
#define O_  256

typedef short    bf16x8 __attribute__((ext_vector_type(8)));
typedef float    f32x16 __attribute__((ext_vector_type(16)));
typedef unsigned u32x4  __attribute__((ext_vector_type(4)));

// xT layout: [b][cc][yphys 0..65][lh 0..1][col 0..65][8c] bf16
#define XROW_SH  1056
#define XBC_SH   (66 * XROW_SH)
#define XT_BYTES ((size_t)B_ * 16 * XBC_SH * 2)

#define WTILE_SH 9216
#define WORP_BYTES ((size_t)B_ * 16 * 4 * WTILE_SH * 2)

#define XBUF_SH  10752

__device__ __forceinline__ unsigned cvtpk(float lo, float hi) {
    unsigned r;
    asm("v_cvt_pk_bf16_f32 %0, %1, %2" : "=v"(r) : "v"(lo), "v"(hi));
    return r;
}

__device__ __forceinline__ void gload16(const void* g, void* l) {
    __builtin_amdgcn_global_load_lds(
        (const __attribute__((address_space(1))) unsigned int*)g,
        (__attribute__((address_space(3))) unsigned int*)l, 16, 0, 0);
}

// ---------------------------------------------------------------- xprep -----
// (r7 version, proven) Thread = 1 pixel x 8 channels: coalesced row loads ->
// cvt_pk -> one 16B store in conv layout. Pool partials fused.
__global__ __launch_bounds__(256) void xprep_kernel(const float* __restrict__ x,
                                                    short* __restrict__ xT,
                                                    float* __restrict__ pooled4) {
    const int cg = blockIdx.x;
    const int b  = blockIdx.y;
    const int z  = blockIdx.z;
    const int t  = threadIdx.x;
    const int lane = t & 63, wv = t >> 6;
    const int cc = cg >> 1, lh = cg & 1;

    short* xTb = xT + (size_t)(b * 16 + cc) * XBC_SH;
    const float* xb = x + ((size_t)(b * C_ + cg * 8) << 12);

    {   // halo zeros for this (cc,lh) slice
        u32x4 zv = {0, 0, 0, 0};
        if (t < 32) {
            int r   = z * 16 + 1 + (t >> 1);
            int col = (t & 1) ? 65 : 0;
            *(u32x4*)&xTb[r * XROW_SH + lh * 528 + col * 8] = zv;
        }
        if (z == 0 || z == 3) {
            int row = (z == 0) ? 0 : 65;
            if (t < 66) *(u32x4*)&xTb[row * XROW_SH + lh * 528 + t * 8] = zv;
        }
    }

    float s[8] = {0.f, 0.f, 0.f, 0.f, 0.f, 0.f, 0.f, 0.f};
    const int px = lane;
#pragma unroll
    for (int r = 0; r < 4; ++r) {
        const int row = z * 16 + wv * 4 + r;
        const float* src = xb + row * 64 + px;
        float v[8];
#pragma unroll
        for (int i = 0; i < 8; ++i) { v[i] = src[(size_t)i << 12]; s[i] += v[i]; }
        u32x4 d = { cvtpk(v[0], v[1]), cvtpk(v[2], v[3]),
                    cvtpk(v[4], v[5]), cvtpk(v[6], v[7]) };
        *(u32x4*)&xTb[(row + 1) * XROW_SH + lh * 528 + (px + 1) * 8] = d;
    }

#pragma unroll
    for (int i = 0; i < 8; ++i)
#pragma unroll
        for (int off = 32; off; off >>= 1) s[i] += __shfl_xor(s[i], off, 64);

    __shared__ float pr[4][8];
    if (lane == 0) {
#pragma unroll
        for (int i = 0; i < 8; ++i) pr[wv][i] = s[i];
    }
    __syncthreads();
    if (t < 8) {
        float v = pr[0][t] + pr[1][t] + pr[2][t] + pr[3][t];
        pooled4[(z * B_ + b) * C_ + cg * 8 + t] = v * (1.0f / 4096.0f);
    }
}

// ---------------------------------------------------------------- mix -------
// Dedup'd AND parallel: grid (cc=16, og=16) = 256 blocks, 4 oc each. Each
// block stages its bank slice ONCE (9.2 KB; bank L2 traffic 150 MB -> 9.4 MB),
// mixes per (oc,c) once per b, scatters to all 4 rotations (mixed value is
// rotation-invariant; only dest tap index permutes). Coeffs: 256-thread
// parallel dot (64 (b,k)-pairs x 4 c-segments).
__global__ __launch_bounds__(256) void mix_kernel(const float* __restrict__ bank,
                                                  const float* __restrict__ pooled4,
                                                  const float* __restrict__ W_fc,
                                                  const float* __restrict__ b_fc,
                                                  short* __restrict__ worp) {
    const int cc = blockIdx.x;   // channel-16 group
    const int og = blockIdx.y;   // oc-4 group
    const int t  = threadIdx.x;

    __shared__ float bankL[4][4][16][10];   // [k][oc4][c16][tap pad10] 10,240 B
    __shared__ float pl[64][4];
    __shared__ float cfs[16][4];

    // ---- stage bank slice (2304 floats, 576B runs)
    for (int i = t; i < 2304; i += 256) {
        int k  = i / 576, r = i % 576;
        int oc = r / 144, r2 = r % 144;
        int c  = r2 / 9,  tap = r2 % 9;
        bankL[k][oc][c][tap] =
            bank[(((size_t)k * 64 + og * 4 + oc) * C_ + cc * 16 + c) * 9 + tap];
    }
    // ---- routing coeffs, 256-thread parallel
    {
        int pair = t >> 2, seg = t & 3;      // pair = b*4+k
        int b = pair >> 2, k = pair & 3;
        float s = 0.f;
        for (int ci = 0; ci < 64; ++ci) {
            int c = seg * 64 + ci;
            float pv = pooled4[b * C_ + c] + pooled4[(B_ + b) * C_ + c]
                     + pooled4[(2 * B_ + b) * C_ + c] + pooled4[(3 * B_ + b) * C_ + c];
            s += pv * W_fc[k * C_ + c];
        }
        pl[pair][seg] = s;
    }
    __syncthreads();
    if (t < 64) {
        int b = t >> 2, k = t & 3;
        cfs[b][k] = pl[t][0] + pl[t][1] + pl[t][2] + pl[t][3] + b_fc[k];
    }
    __syncthreads();
    if (t < 16) {
        float l0 = cfs[t][0], l1 = cfs[t][1], l2 = cfs[t][2], l3 = cfs[t][3];
        float mx = fmaxf(fmaxf(l0, l1), fmaxf(l2, l3));
        float e0 = expf(l0 - mx), e1 = expf(l1 - mx);
        float e2 = expf(l2 - mx), e3 = expf(l3 - mx);
        float inv = 1.f / (e0 + e1 + e2 + e3);
        cfs[t][0] = e0 * inv; cfs[t][1] = e1 * inv;
        cfs[t][2] = e2 * inv; cfs[t][3] = e3 * inv;
    }
    __syncthreads();

    // thread -> (oc_l, lhs, b, rep); rep is wave-uniform (t>>7)
    const int oc_l = t & 3;
    const int lhs  = (t >> 2) & 1;
    const int b    = (t >> 3) & 15;
    const int rep  = t >> 7;                 // 0 -> oq{0,1}, 1 -> oq{2,3}
    const int o64  = og * 4 + oc_l;

    const float c0 = cfs[b][0], c1 = cfs[b][1], c2 = cfs[b][2], c3 = cfs[b][3];
    float mixed[8][9];
#pragma unroll
    for (int ci = 0; ci < 8; ++ci)
#pragma unroll
        for (int tp = 0; tp < 9; ++tp)
            mixed[ci][tp] = c0 * bankL[0][oc_l][lhs * 8 + ci][tp]
                          + c1 * bankL[1][oc_l][lhs * 8 + ci][tp]
                          + c2 * bankL[2][oc_l][lhs * 8 + ci][tp]
                          + c3 * bankL[3][oc_l][lhs * 8 + ci][tp];

    // STOREOQ(oq literal): dest td=(ti,tj) <- src (si,sj)=rot^-1(ti,tj)
#define STOREOQ(OQ)                                                             \
    _Pragma("unroll")                                                           \
    for (int td = 0; td < 9; ++td) {                                            \
        const int ti = td / 3, tj = td % 3;                                     \
        int si, sj;                                                             \
        if      ((OQ) == 0) { si = ti;     sj = tj;     }                       \
        else if ((OQ) == 1) { si = tj;     sj = 2 - ti; }                       \
        else if ((OQ) == 2) { si = 2 - ti; sj = 2 - tj; }                       \
        else                { si = 2 - tj; sj = ti;     }                       \
        const int ts = si * 3 + sj;                                             \
        u32x4 d = { cvtpk(mixed[0][ts], mixed[1][ts]),                          \
                    cvtpk(mixed[2][ts], mixed[3][ts]),                          \
                    cvtpk(mixed[4][ts], mixed[5][ts]),                          \
                    cvtpk(mixed[6][ts], mixed[7][ts]) };                        \
        size_t base = ((((((size_t)b * 16 + cc) * 4 + (OQ)) * 9 + td) * 2       \
                        + lhs) * 64 + o64) * 8;                                 \
        *(u32x4*)&worp[base] = d;                                               \
    }

    if (rep == 0) { STOREOQ(0) STOREOQ(1) }
    else          { STOREOQ(2) STOREOQ(3) }
#undef STOREOQ
}

// ---------------------------------------------------------------- conv ------
// (r5 version, proven 66.8 us) 64 o x 512 px per block, 4 waves; gload_lds
// double-buffer, 1 barrier/chunk; B-rows register-cached across tap-rows.
__global__ __launch_bounds__(256, 2)
void conv_mfma(const short* __restrict__ xT, const short* __restrict__ worp,
               float* __restrict__ out) {
    __shared__ short lds[2 * XBUF_SH + 2 * WTILE_SH];

    const int g    = blockIdx.x;
    const int w    = (g & 7) * 64 + (g >> 3);
    const int oq   = w & 3;
    const int m    = w >> 2;
    const int rowt = m & 7;
    const int b    = m >> 3;
    const int y0   = rowt * 8;

    const int t    = threadIdx.x;
    const int lane = t & 63;
    const int wid  = t >> 6;
    const int l31  = lane & 31;
    const int lh   = lane >> 5;

    const char* xsrcB = (const char*)xT
        + ((size_t)(b * 16) * XBC_SH + (size_t)y0 * XROW_SH) * 2 + lane * 16;
    const char* wsrcB = (const char*)worp
        + (((size_t)(b * 16) * 4) + oq) * (WTILE_SH * 2) + lane * 16;

#define STAGE(ccc, p)                                                           \
    { const char* xs = xsrcB + (size_t)(ccc) * (XBC_SH * 2);                    \
      const char* ws = wsrcB + (size_t)(ccc) * (4 * WTILE_SH * 2);              \
      char* xd = (char*)lds + (p) * (XBUF_SH * 2);                              \
      char* wd = (char*)lds + 2 * (XBUF_SH * 2) + (p) * (WTILE_SH * 2);         \
      for (int u = wid; u < 21; u += 4) gload16(xs + u * 1024, xd + u * 1024);  \
      for (int u = wid; u < 18; u += 4) gload16(ws + u * 1024, wd + u * 1024); }

#define BRD(r, s) (*(const bf16x8*)&xcur[(((r) * 2 + lh) * 66 + (s) + l31) * 8])
#define LOADROW(R, r)                                                           \
    { R[0] = BRD(r, 0);  R[1] = BRD(r, 1);  R[2] = BRD(r, 2);                   \
      R[3] = BRD(r, 32); R[4] = BRD(r, 33); R[5] = BRD(r, 34); }

#define TAPROW(i, RA, RB)                                                       \
    _Pragma("unroll")                                                           \
    for (int j = 0; j < 3; ++j) {                                               \
        const int tap = (i) * 3 + j;                                            \
        const short* wp = wcur + ((tap * 2 + lh) * 64 + l31) * 8;               \
        bf16x8 A0 = *(const bf16x8*)wp;                                         \
        bf16x8 A1 = *(const bf16x8*)(wp + 256);                                 \
        acc0[0] = __builtin_amdgcn_mfma_f32_32x32x16_bf16(A0, RA[j],     acc0[0], 0, 0, 0); \
        acc1[0] = __builtin_amdgcn_mfma_f32_32x32x16_bf16(A1, RA[j],     acc1[0], 0, 0, 0); \
        acc0[1] = __builtin_amdgcn_mfma_f32_32x32x16_bf16(A0, RA[3 + j], acc0[1], 0, 0, 0); \
        acc1[1] = __builtin_amdgcn_mfma_f32_32x32x16_bf16(A1, RA[3 + j], acc1[1], 0, 0, 0); \
        acc0[2] = __builtin_amdgcn_mfma_f32_32x32x16_bf16(A0, RB[j],     acc0[2], 0, 0, 0); \
        acc1[2] = __builtin_amdgcn_mfma_f32_32x32x16_bf16(A1, RB[j],     acc1[2], 0, 0, 0); \
        acc0[3] = __builtin_amdgcn_mfma_f32_32x32x16_bf16(A0, RB[3 + j], acc0[3], 0, 0, 0); \
        acc1[3] = __builtin_amdgcn_mfma_f32_32x32x16_bf16(A1, RB[3 + j], acc1[3], 0, 0, 0); \
    }

    f32x16 acc0[4] = {}, acc1[4] = {};

    STAGE(0, 0);
    __syncthreads();

    for (int cc = 0; cc < 16; ++cc) {
        const int p = cc & 1;
        if (cc < 15) STAGE(cc + 1, p ^ 1);
        const short* xcur = lds + p * XBUF_SH;
        const short* wcur = lds + 2 * XBUF_SH + p * WTILE_SH;

        bf16x8 R0[6], R1[6];
        __builtin_amdgcn_s_setprio(1);
        LOADROW(R0, 2 * wid);
        LOADROW(R1, 2 * wid + 1);
        TAPROW(0, R0, R1)
        LOADROW(R0, 2 * wid + 2)
        TAPROW(1, R1, R0)
        LOADROW(R1, 2 * wid + 3)
        TAPROW(2, R0, R1)
        __builtin_amdgcn_s_setprio(0);
        __syncthreads();
    }
#undef STAGE
#undef BRD
#undef LOADROW
#undef TAPROW

#pragma unroll
    for (int pf = 0; pf < 4; ++pf) {
        const int yb  = y0 + 2 * wid + (pf >> 1);
        const int xcb = 32 * (pf & 1) + l31;
#pragma unroll
        for (int r = 0; r < 16; ++r) {
            const int orow = (r & 3) + 8 * (r >> 2) + 4 * lh;
            const int o0   = oq * 64 + orow;
            __builtin_nontemporal_store(acc0[pf][r],
                &out[((size_t)(b * O_ + o0)      << 12) + yb * 64 + xcb]);
            __builtin_nontemporal_store(acc1[pf][r],
                &out[((size_t)(b * O_ + o0 + 32) << 12) + yb * 64 + xcb]);
        }
    }
}

// ---------------------------------------------------------------- launch ----
extern "C" void kernel_launch(void* const* d_in, const int* in_sizes, int n_in,
                              void* d_out, int out_size, void* d_ws, size_t ws_size,
                              hipStream_t stream) {
    const float* x    = (const float*)d_in[0];
    const float* W_fc = (const float*)d_in[1];
    const float* b_fc = (const float*)d_in[2];
    const float* bank = (const float*)d_in[3];
    float* out = (float*)d_out;

    short* xTb     = (short*)d_ws;
    short* worp    = (short*)((char*)d_ws + XT_BYTES);
    float* pooled4 = (float*)((char*)d_ws + XT_BYTES + WORP_BYTES);

    xprep_kernel<<<dim3(32, 16, 4), 256, 0, stream>>>(x, xTb, pooled4);
    mix_kernel<<<dim3(16, 16), 256, 0, stream>>>(bank, pooled4, W_fc, b_fc, worp);
    conv_mfma<<<512, 256, 0, stream>>>(xTb, worp, out);
}